// Round 11
// baseline (159.560 us; speedup 1.0000x reference)
//
#include <hip/hip_runtime.h>

// NeurTWs R11 = R10 (62us, no spill, barrier-free iters) + software
// pipeline of the serial memory chain. R10's counters showed ~55% idle
// waiting on idx->gather (two dependent global round-trips per iter).
// Per iter VMEM issue order (so no s_waitcnt drains younger loads):
//   1) next-iter ndrN[4]+kkN          (oldest)
//   2) this-iter feat gathers (addresses rotated in from last iter)
//   3) GEMM1 uses enc ALREADY IN REGS (zero wait)
//   4) encN = pos_table[kkN] issued after ktile0 (kkN landed; vmcnt(8))
//   5) GEMM3 ktile1/2 wait on feat = vmcnt(1)
// Rotation state = ndr[4]+kk+enc[4] = 9 regs (84 -> ~95; 3-wave budget
// is ~170 -> no spill). R8's spill was the Wfuse lineage (R9 spilled
// without prefetch), not rotation per se.
// Fragment layouts (gfx950, verified): A/B: idx=lane&15, k=(lane>>4)*8+j;
// C/D: col=lane&15, row=(lane>>4)*4+reg.

typedef _Float16 half8 __attribute__((ext_vector_type(8)));
typedef float floatx4 __attribute__((ext_vector_type(4)));

#define HSTR 40    // h/pe row stride (f16): 80 B
#define WSTR 104   // wm1t row stride (f16): 208 B
#define GRID_MAIN 768
#define STEP (GRID_MAIN * 256)

__global__ void feat_to_f16(const float* __restrict__ nf,
                            _Float16* __restrict__ o, int n8) {
    int t = blockIdx.x * 256 + threadIdx.x;
    if (t >= n8) return;
    const float4* p = (const float4*)nf + (size_t)t * 2;
    const float4 a = p[0], b = p[1];
    half8 h;
    h[0] = (_Float16)a.x; h[1] = (_Float16)a.y;
    h[2] = (_Float16)a.z; h[3] = (_Float16)a.w;
    h[4] = (_Float16)b.x; h[5] = (_Float16)b.y;
    h[6] = (_Float16)b.z; h[7] = (_Float16)b.w;
    *((half8*)o + t) = h;
}

__global__ __launch_bounds__(256, 3) void neurtw_r11(
    const float* __restrict__ pos_table,   // [NUM_KEYS, 4]
    const float* __restrict__ node_feat,   // [NUM_NODES, 64] fp32 (fallback)
    const float* __restrict__ W1,          // [4, 32]
    const float* __restrict__ b1,          // [32]
    const float* __restrict__ W2,          // [32, 32]
    const float* __restrict__ b2,          // [32]
    const float* __restrict__ Wm1,         // [96, 64]
    const float* __restrict__ bm1,         // [64]
    const float* __restrict__ Wm2,         // [64, 1]
    const float* __restrict__ bm2,         // [1]
    const int*   __restrict__ key_idx,     // [rows]
    const int*   __restrict__ node_idx,    // [rows]
    const _Float16* __restrict__ feat16,   // [NUM_NODES, 64] f16 (ws)
    int use_f16,
    float*       __restrict__ out,         // [rows]
    int rows)
{
    __shared__ _Float16 hpe[256 * HSTR];   // 20 KB (h then pe; wave-private)
    __shared__ _Float16 wm1t[64 * WSTR];   // 13 KB  wm1t[n][k] = Wm1[k][n]

    const int tid  = threadIdx.x;
    const int lane = tid & 63;
    const int r0   = (tid >> 6) * 64;
    const int ln   = lane & 15;
    const int q    = lane >> 4;

    // ---------- once per block: stage Wm1^T into LDS ----------
    #pragma unroll
    for (int i = 0; i < 3; ++i) {
        const int task = i * 256 + tid;
        const int n = task & 63, k8 = task >> 6;
        half8 w;
        #pragma unroll
        for (int kk2 = 0; kk2 < 8; ++kk2)
            w[kk2] = (_Float16)Wm1[(k8 * 8 + kk2) * 64 + n];
        *(half8*)(&wm1t[n * WSTR + k8 * 8]) = w;
    }

    // ---------- once per block: per-lane weight/bias fragments ----------
    half8 b_w2[2];
    #pragma unroll
    for (int ct = 0; ct < 2; ++ct)
        #pragma unroll
        for (int j = 0; j < 8; ++j)
            b_w2[ct][j] = (_Float16)W2[(q * 8 + j) * 32 + ct * 16 + ln];
    float b2v[2];
    b2v[0] = b2[ln]; b2v[1] = b2[16 + ln];
    float bm1v[4], wm2v[4];
    #pragma unroll
    for (int ct = 0; ct < 4; ++ct) {
        bm1v[ct] = bm1[ct * 16 + ln];
        wm2v[ct] = Wm2[ct * 16 + ln];
    }
    const float bm2s = bm2[0];

    __syncthreads();   // wm1t staged (the ONLY barrier in the kernel)

    // ---------- pipeline prologue: iter-0 idx + enc ----------
    int base = blockIdx.x * 256;
    int ndr[4] = {0, 0, 0, 0};
    float4 enc = {0.f, 0.f, 0.f, 0.f};
    if (base < rows) {
        #pragma unroll
        for (int rt = 0; rt < 4; ++rt)
            ndr[rt] = node_idx[base + r0 + rt * 16 + ln];
        const int kk0 = key_idx[base + tid];
        enc = *(const float4*)(pos_table + (size_t)kk0 * 4);
    }

    while (base < rows) {
        const int nbase = base + STEP;

        // ---- (1) next-iter index loads FIRST (oldest in vmcnt queue) ----
        int ndrN[4] = {0, 0, 0, 0};
        int kkN = 0;
        if (nbase < rows) {
            #pragma unroll
            for (int rt = 0; rt < 4; ++rt)
                ndrN[rt] = node_idx[nbase + r0 + rt * 16 + ln];
            kkN = key_idx[nbase + tid];
        }

        // ---- (2) this-iter feat gathers: addresses already in regs ----
        half8 fA[4][2];
        if (use_f16) {
            #pragma unroll
            for (int rt = 0; rt < 4; ++rt) {
                const _Float16* fb = feat16 + (size_t)ndr[rt] * 64 + q * 8;
                fA[rt][0] = *(const half8*)(fb);
                fA[rt][1] = *(const half8*)(fb + 32);
            }
        } else {
            #pragma unroll
            for (int rt = 0; rt < 4; ++rt) {
                const float* fb = node_feat + (size_t)ndr[rt] * 64 + q * 8;
                #pragma unroll
                for (int kt = 0; kt < 2; ++kt) {
                    const float4 lo = *(const float4*)(fb + kt * 32);
                    const float4 hi = *(const float4*)(fb + kt * 32 + 4);
                    half8 h;
                    h[0] = (_Float16)lo.x; h[1] = (_Float16)lo.y;
                    h[2] = (_Float16)lo.z; h[3] = (_Float16)lo.w;
                    h[4] = (_Float16)hi.x; h[5] = (_Float16)hi.y;
                    h[6] = (_Float16)hi.z; h[7] = (_Float16)hi.w;
                    fA[rt][kt] = h;
                }
            }
        }

        // ---- (3) GEMM1: enc already resident, zero memory wait ----
        #pragma unroll
        for (int g = 0; g < 4; ++g) {
            half8 hv;
            #pragma unroll
            for (int j8 = 0; j8 < 8; ++j8) {
                const int j = g * 8 + j8;
                float a = fmaf(enc.w, W1[96 + j],
                          fmaf(enc.z, W1[64 + j],
                          fmaf(enc.y, W1[32 + j],
                          fmaf(enc.x, W1[j], b1[j]))));
                hv[j8] = (_Float16)fmaxf(a, 0.0f);
            }
            *(half8*)(&hpe[tid * HSTR + g * 8]) = hv;
        }
        // wave-private transpose read — no barrier (same wave wrote it)
        half8 a_h[4];
        #pragma unroll
        for (int rt = 0; rt < 4; ++rt)
            a_h[rt] = *(const half8*)(&hpe[(r0 + rt * 16 + ln) * HSTR + q * 8]);

        // ---- GEMM2: 8 MFMA -> pe (C-layout regs) ----
        floatx4 pc[4][2];
        #pragma unroll
        for (int rt = 0; rt < 4; ++rt)
            #pragma unroll
            for (int ct = 0; ct < 2; ++ct) {
                floatx4 c = {0.f, 0.f, 0.f, 0.f};
                pc[rt][ct] = __builtin_amdgcn_mfma_f32_16x16x32_f16(
                    a_h[rt], b_w2[ct], c, 0, 0, 0);
            }

        // write pe into the SAME buffer (h consumed; own wave's slice only)
        #pragma unroll
        for (int rt = 0; rt < 4; ++rt)
            #pragma unroll
            for (int ct = 0; ct < 2; ++ct)
                #pragma unroll
                for (int r = 0; r < 4; ++r)
                    hpe[(r0 + rt * 16 + q * 4 + r) * HSTR + ct * 16 + ln] =
                        (_Float16)(pc[rt][ct][r] + b2v[ct]);
        // no barrier: reader below is the same wave

        // ---- GEMM3 ----
        floatx4 acc[4][4];
        #pragma unroll
        for (int ct = 0; ct < 4; ++ct) {
            const float bb = bm1v[ct];
            #pragma unroll
            for (int rt = 0; rt < 4; ++rt)
                acc[rt][ct] = (floatx4){bb, bb, bb, bb};
        }

        {   // ktile 0: A = pe from LDS
            half8 a_pe[4];
            #pragma unroll
            for (int rt = 0; rt < 4; ++rt)
                a_pe[rt] = *(const half8*)(&hpe[(r0 + rt * 16 + ln) * HSTR + q * 8]);
            half8 b0[4];
            #pragma unroll
            for (int ct = 0; ct < 4; ++ct)
                b0[ct] = *(const half8*)(&wm1t[(ct * 16 + ln) * WSTR + q * 8]);
            #pragma unroll
            for (int rt = 0; rt < 4; ++rt)
                #pragma unroll
                for (int ct = 0; ct < 4; ++ct)
                    acc[rt][ct] = __builtin_amdgcn_mfma_f32_16x16x32_f16(
                        a_pe[rt], b0[ct], acc[rt][ct], 0, 0, 0);
        }

        // ---- (4) issue next-iter enc gather: kkN landed (vmcnt(8) free),
        //      feat gathers (younger) stay in flight ----
        float4 encN = {0.f, 0.f, 0.f, 0.f};
        if (nbase < rows)
            encN = *(const float4*)(pos_table + (size_t)kkN * 4);

        // ---- (5) ktiles 1,2: A = feat (wait = vmcnt(1): encN in flight) ----
        #pragma unroll
        for (int kt = 0; kt < 2; ++kt) {
            half8 bk[4];
            #pragma unroll
            for (int ct = 0; ct < 4; ++ct)
                bk[ct] = *(const half8*)(&wm1t[(ct * 16 + ln) * WSTR + 32 + kt * 32 + q * 8]);
            #pragma unroll
            for (int rt = 0; rt < 4; ++rt)
                #pragma unroll
                for (int ct = 0; ct < 4; ++ct)
                    acc[rt][ct] = __builtin_amdgcn_mfma_f32_16x16x32_f16(
                        fA[rt][kt], bk[ct], acc[rt][ct], 0, 0, 0);
        }

        // ---- GEMM4: relu + Wm2 dot + 4-step butterfly + store ----
        #pragma unroll
        for (int rt = 0; rt < 4; ++rt) {
            #pragma unroll
            for (int r = 0; r < 4; ++r) {
                float p = 0.0f;
                #pragma unroll
                for (int ct = 0; ct < 4; ++ct)
                    p = fmaf(fmaxf(acc[rt][ct][r], 0.0f), wm2v[ct], p);
                p += __shfl_xor(p, 1);
                p += __shfl_xor(p, 2);
                p += __shfl_xor(p, 4);
                p += __shfl_xor(p, 8);
                if (ln == 0)
                    out[base + r0 + rt * 16 + q * 4 + r] = p + bm2s;
            }
        }

        // ---- rotate pipeline state (9 regs) ----
        base = nbase;
        #pragma unroll
        for (int rt = 0; rt < 4; ++rt) ndr[rt] = ndrN[rt];
        enc = encN;
    }
}

extern "C" void kernel_launch(void* const* d_in, const int* in_sizes, int n_in,
                              void* d_out, int out_size, void* d_ws, size_t ws_size,
                              hipStream_t stream) {
    const float* pos_table = (const float*)d_in[0];
    const float* node_feat = (const float*)d_in[1];
    const float* W1        = (const float*)d_in[2];
    const float* b1        = (const float*)d_in[3];
    const float* W2        = (const float*)d_in[4];
    const float* b2        = (const float*)d_in[5];
    const float* Wm1       = (const float*)d_in[6];
    const float* bm1       = (const float*)d_in[7];
    const float* Wm2       = (const float*)d_in[8];
    const float* bm2       = (const float*)d_in[9];
    const int*   key_idx   = (const int*)d_in[10];
    const int*   node_idx  = (const int*)d_in[11];
    float* out = (float*)d_out;

    const int rows  = in_sizes[10];                // 1,048,576
    const int nfeat = in_sizes[1];                 // NUM_NODES*64

    _Float16* feat16 = (_Float16*)d_ws;
    const size_t need = (size_t)nfeat * sizeof(_Float16);
    const int use_f16 = (ws_size >= need) ? 1 : 0;

    if (use_f16) {
        const int n8 = nfeat / 8;
        feat_to_f16<<<(n8 + 255) / 256, 256, 0, stream>>>(node_feat, feat16, n8);
    }

    neurtw_r11<<<GRID_MAIN, 256, 0, stream>>>(
        pos_table, node_feat, W1, b1, W2, b2, Wm1, bm1, Wm2, bm2,
        key_idx, node_idx, feat16, use_f16, out, rows);
}